// Round 1
// baseline (397.590 us; speedup 1.0000x reference)
//
#include <hip/hip_runtime.h>
#include <math.h>

#define B_    64
#define KP1   16385      // K+1
#define D_    128
#define N_    500000
#define INV_T (1.0f / 0.07f)
#define MOM_  0.5f

#define SPLIT 128
#define CHUNK 129        // ceil(KP1 / SPLIT)

// One block per b; wave 0 updates memory_l row, wave 1 updates memory_ab row.
__global__ __launch_bounds__(128)
void ema_update_kernel(const float* __restrict__ l,
                       const float* __restrict__ ab,
                       const float* __restrict__ mem_l,
                       const float* __restrict__ mem_ab,
                       const int* __restrict__ y,
                       float* __restrict__ out_mem_l,
                       float* __restrict__ out_mem_ab) {
    const int b    = blockIdx.x;
    const int wave = threadIdx.x >> 6;   // 0: l-bank, 1: ab-bank
    const int lane = threadIdx.x & 63;
    const int yb   = y[b];

    const float* mem  = wave ? mem_ab    : mem_l;
    const float* feat = wave ? ab        : l;
    float*       om   = wave ? out_mem_ab : out_mem_l;

    const float2* mrow = (const float2*)(mem  + (size_t)yb * D_);
    const float2* frow = (const float2*)(feat + (size_t)b  * D_);
    float2 m2 = mrow[lane];
    float2 f2 = frow[lane];

    float px = m2.x * MOM_ + f2.x * (1.0f - MOM_);
    float py = m2.y * MOM_ + f2.y * (1.0f - MOM_);
    float ss = px * px + py * py;
    #pragma unroll
    for (int m = 32; m >= 1; m >>= 1) ss += __shfl_xor(ss, m);
    float rn = 1.0f / sqrtf(ss);

    float2* orow = (float2*)(om + (size_t)yb * D_);
    orow[lane] = make_float2(px * rn, py * rn);
}

// grid = (B, SPLIT), block = 256 (8 groups of 32 lanes).
// Each 32-lane group computes one dot(mem_row[idx], feat)/T per iteration.
// Even groups: out_l = memory_ab[idx] . l ; odd groups: out_ab = memory_l[idx] . ab
__global__ __launch_bounds__(256)
void score_kernel(const float* __restrict__ l,
                  const float* __restrict__ ab,
                  const float* __restrict__ mem_l,
                  const float* __restrict__ mem_ab,
                  const int* __restrict__ idx,
                  float* __restrict__ out) {
    const int b     = blockIdx.x;
    const int group = threadIdx.x >> 5;   // 0..7
    const int glane = threadIdx.x & 31;
    const int k0    = blockIdx.y * CHUNK;

    // feature fragments held in registers for the whole block's lifetime
    const float4 l4  = ((const float4*)(l  + (size_t)b * D_))[glane];
    const float4 ab4 = ((const float4*)(ab + (size_t)b * D_))[glane];

    const size_t BK = (size_t)B_ * KP1;

    for (int i = group; i < CHUNK * 2; i += 8) {
        const int k = k0 + (i >> 1);
        if (k >= KP1) break;                 // i>>1 is monotone per group
        const int bank = i & 1;              // constant per group (stride 8)
        const int ridx = idx[(size_t)b * KP1 + k];

        const float4* row =
            (const float4*)((bank ? mem_l : mem_ab) + (size_t)ridx * D_);
        const float4 r = row[glane];
        const float4 f = bank ? ab4 : l4;

        float v = r.x * f.x + r.y * f.y + r.z * f.z + r.w * f.w;
        #pragma unroll
        for (int m = 16; m >= 1; m >>= 1) v += __shfl_xor(v, m);

        if (glane == 0)
            out[(size_t)bank * BK + (size_t)b * KP1 + k] = v * INV_T;
    }
}

extern "C" void kernel_launch(void* const* d_in, const int* in_sizes, int n_in,
                              void* d_out, int out_size, void* d_ws, size_t ws_size,
                              hipStream_t stream) {
    const float* l      = (const float*)d_in[0];
    const float* ab     = (const float*)d_in[1];
    const float* mem_l  = (const float*)d_in[2];
    const float* mem_ab = (const float*)d_in[3];
    const int*   y      = (const int*)d_in[4];
    const int*   idx    = (const int*)d_in[5];
    float* out = (float*)d_out;

    const size_t BK = (size_t)B_ * KP1;
    float* out_mem_l  = out + 2 * BK;
    float* out_mem_ab = out_mem_l + (size_t)N_ * D_;

    // 1) copy banks into output regions (bulk of new_memory_* is unchanged)
    hipMemcpyAsync(out_mem_l,  mem_l,  (size_t)N_ * D_ * sizeof(float),
                   hipMemcpyDeviceToDevice, stream);
    hipMemcpyAsync(out_mem_ab, mem_ab, (size_t)N_ * D_ * sizeof(float),
                   hipMemcpyDeviceToDevice, stream);

    // 2) EMA + L2-normalize the B updated rows (reads ORIGINAL banks from d_in)
    ema_update_kernel<<<B_, 128, 0, stream>>>(l, ab, mem_l, mem_ab, y,
                                              out_mem_l, out_mem_ab);

    // 3) scoring: out_l = mem_ab[idx].l / T ; out_ab = mem_l[idx].ab / T
    score_kernel<<<dim3(B_, SPLIT), 256, 0, stream>>>(l, ab, mem_l, mem_ab,
                                                      idx, out);
}